// Round 7
// baseline (558.086 us; speedup 1.0000x reference)
//
#include <hip/hip_runtime.h>
#include <stdint.h>

typedef unsigned short u16;
typedef __bf16 bf16x8 __attribute__((ext_vector_type(8)));
typedef float f32x4 __attribute__((ext_vector_type(4)));

#define D_MODEL 4096
#define T_SEQ   2048
#define B_SZ    2
#define NH      32
#define NKV     8
#define HDIM    128
#define WINDOW  1024
#define NGLOB   32
#define QSTR    6144   // fused qkv row stride: [q 4096 | k 1024 | v 1024]

static constexpr float SCALE = 0.08838834764831845f; // 1/sqrt(128)

__device__ __forceinline__ u16 f2b(float f) {
  __bf16 h = (__bf16)f;
  return __builtin_bit_cast(u16, h);
}

// ---------------- x f32 -> bf16 (vectorized) ----------------
__global__ __launch_bounds__(256) void convert_bf16_kernel(const float* __restrict__ in,
                                                           u16* __restrict__ outp, int n4) {
  int i = blockIdx.x * 256 + threadIdx.x;
  if (i >= n4) return;
  float4 v = ((const float4*)in)[i];
  ushort4 o;
  o.x = f2b(v.x); o.y = f2b(v.y); o.z = f2b(v.z); o.w = f2b(v.w);
  ((ushort4*)outp)[i] = o;
}

// ---------------- W [K,N] f32 -> Wt [N,K] bf16 ----------------
__global__ __launch_bounds__(256) void transpose_w_kernel(const float* __restrict__ W,
                                                          u16* __restrict__ Wt, int Kd, int Nd) {
  __shared__ float tile[32][33];
  int tx = threadIdx.x & 31, ty = threadIdx.x >> 5;
  int bx = blockIdx.x * 32; // N
  int by = blockIdx.y * 32; // K
#pragma unroll
  for (int i = 0; i < 4; ++i)
    tile[ty + i * 8][tx] = W[(size_t)(by + ty + i * 8) * Nd + bx + tx];
  __syncthreads();
#pragma unroll
  for (int i = 0; i < 4; ++i)
    Wt[(size_t)(bx + ty + i * 8) * Kd + by + tx] = f2b(tile[tx][ty + i * 8]);
}

// ---------------- v slice of qkv -> vT [B][KH*HD][T] bf16 ----------------
__global__ __launch_bounds__(256) void transpose_v_kernel(const u16* __restrict__ in,
                                                          u16* __restrict__ outp) {
  __shared__ u16 tile[32][33];
  int tx = threadIdx.x & 31, ty = threadIdx.x >> 5;
  int x0 = blockIdx.x * 32; // hd' = kh*128+hd (0..1023)
  int t0 = blockIdx.y * 32; // t
  int b = blockIdx.z;
  const u16* src = in + (size_t)b * T_SEQ * QSTR;
  u16* dst = outp + (size_t)b * (NKV * HDIM) * T_SEQ;
#pragma unroll
  for (int i = 0; i < 4; ++i)
    tile[ty + i * 8][tx] = src[(size_t)(t0 + ty + i * 8) * QSTR + x0 + tx];
  __syncthreads();
#pragma unroll
  for (int i = 0; i < 4; ++i)
    dst[(size_t)(x0 + ty + i * 8) * T_SEQ + t0 + tx] = tile[tx][ty + i * 8];
}

// ---------------- 256x256 8-phase bf16 GEMM (proven): C = A @ Bt^T ----------------
template <typename CT>
__global__ __launch_bounds__(512, 2) void gemm256_kernel(const u16* __restrict__ A,
                                                         const u16* __restrict__ Bt,
                                                         CT* __restrict__ C,
                                                         int ldc, int K) {
  __shared__ u16 sh[65536]; // [buf:2][A 16384 | B 16384] u16 = 128 KiB
  const int tid = threadIdx.x;
  const int wave = tid >> 6, lane = tid & 63;
  const int g = lane >> 4, li = lane & 15;
  const int wr = wave >> 2, wc = wave & 3;
  const int m0 = blockIdx.y * 256, n0 = blockIdx.x * 256;
  const int r0 = tid >> 3;
  const int cs = ((tid & 7) ^ ((tid >> 3) & 7)) << 3;
  const u16* pA = A + (size_t)(m0 + r0) * K + cs;
  const u16* pB = Bt + (size_t)(n0 + r0) * K + cs;
  const int sl0 = (g ^ (li & 7)) << 3;
  const int sl1 = ((4 + g) ^ (li & 7)) << 3;
  const int nT = K >> 6;

  f32x4 acc[8][4];
  f32x4 zz = {0.f, 0.f, 0.f, 0.f};
#pragma unroll
  for (int M = 0; M < 8; ++M)
#pragma unroll
    for (int n = 0; n < 4; ++n) acc[M][n] = zz;

  auto stage = [&](const u16* src0, int ts, int dstBase) {
#pragma unroll
    for (int i = 0; i < 2; ++i) {
      const u16* s = src0 + (size_t)(i * 64) * K + ts * 64;
      __builtin_amdgcn_global_load_lds((__attribute__((address_space(1))) void*)s,
                                       (__attribute__((address_space(3))) void*)(sh + dstBase + i * 4096 + wave * 512),
                                       16, 0, 0);
    }
  };

  stage(pA, 0, 0);
  stage(pA + (size_t)128 * K, 0, 8192);
  stage(pB, 0, 16384);
  stage(pB + (size_t)128 * K, 0, 24576);
  stage(pB, 1, 32768 + 16384);
  stage(pB + (size_t)128 * K, 1, 32768 + 24576);
  stage(pA, 1, 32768);
  asm volatile("s_waitcnt vmcnt(6)" ::: "memory");
  __builtin_amdgcn_s_barrier();

  bf16x8 afr[4][2], bfr[4][2];
  for (int t = 0; t < nT; ++t) {
    const int cur = t & 1;
    const int ab = cur * 32768, bb = ab + 16384;
    const int nb = (cur ^ 1) * 32768;
    const int tn1 = (t + 1 < nT) ? t + 1 : nT - 1;
    const int tn2 = (t + 2 < nT) ? t + 2 : nT - 1;
#pragma unroll
    for (int n = 0; n < 4; ++n) {
      int row = wc * 64 + n * 16 + li;
      bfr[n][0] = *(const bf16x8*)&sh[bb + row * 64 + sl0];
      bfr[n][1] = *(const bf16x8*)&sh[bb + row * 64 + sl1];
    }
#pragma unroll
    for (int m = 0; m < 4; ++m) {
      int row = wr * 128 + m * 16 + li;
      afr[m][0] = *(const bf16x8*)&sh[ab + row * 64 + sl0];
      afr[m][1] = *(const bf16x8*)&sh[ab + row * 64 + sl1];
    }
    stage(pA + (size_t)128 * K, tn1, nb + 8192);
    __builtin_amdgcn_s_barrier();
    asm volatile("s_waitcnt lgkmcnt(0)" ::: "memory");
    __builtin_amdgcn_sched_barrier(0);
    __builtin_amdgcn_s_setprio(1);
#pragma unroll
    for (int m = 0; m < 4; ++m)
#pragma unroll
      for (int n = 0; n < 2; ++n) {
        acc[m][n] = __builtin_amdgcn_mfma_f32_16x16x32_bf16(afr[m][0], bfr[n][0], acc[m][n], 0, 0, 0);
        acc[m][n] = __builtin_amdgcn_mfma_f32_16x16x32_bf16(afr[m][1], bfr[n][1], acc[m][n], 0, 0, 0);
      }
    __builtin_amdgcn_s_setprio(0);
    __builtin_amdgcn_s_barrier();
    stage(pB, tn2, bb);
    __builtin_amdgcn_s_barrier();
    __builtin_amdgcn_s_setprio(1);
#pragma unroll
    for (int m = 0; m < 4; ++m)
#pragma unroll
      for (int n = 2; n < 4; ++n) {
        acc[m][n] = __builtin_amdgcn_mfma_f32_16x16x32_bf16(afr[m][0], bfr[n][0], acc[m][n], 0, 0, 0);
        acc[m][n] = __builtin_amdgcn_mfma_f32_16x16x32_bf16(afr[m][1], bfr[n][1], acc[m][n], 0, 0, 0);
      }
    __builtin_amdgcn_s_setprio(0);
    __builtin_amdgcn_s_barrier();
#pragma unroll
    for (int m = 0; m < 4; ++m) {
      int row = wr * 128 + 64 + m * 16 + li;
      afr[m][0] = *(const bf16x8*)&sh[ab + row * 64 + sl0];
      afr[m][1] = *(const bf16x8*)&sh[ab + row * 64 + sl1];
    }
    stage(pB + (size_t)128 * K, tn2, bb + 8192);
    __builtin_amdgcn_s_barrier();
    asm volatile("s_waitcnt lgkmcnt(0)" ::: "memory");
    __builtin_amdgcn_sched_barrier(0);
    __builtin_amdgcn_s_setprio(1);
#pragma unroll
    for (int m = 0; m < 4; ++m)
#pragma unroll
      for (int n = 0; n < 2; ++n) {
        acc[4 + m][n] = __builtin_amdgcn_mfma_f32_16x16x32_bf16(afr[m][0], bfr[n][0], acc[4 + m][n], 0, 0, 0);
        acc[4 + m][n] = __builtin_amdgcn_mfma_f32_16x16x32_bf16(afr[m][1], bfr[n][1], acc[4 + m][n], 0, 0, 0);
      }
    __builtin_amdgcn_s_setprio(0);
    __builtin_amdgcn_s_barrier();
    stage(pA, tn2, ab);
    __builtin_amdgcn_s_barrier();
    __builtin_amdgcn_s_setprio(1);
#pragma unroll
    for (int m = 0; m < 4; ++m)
#pragma unroll
      for (int n = 2; n < 4; ++n) {
        acc[4 + m][n] = __builtin_amdgcn_mfma_f32_16x16x32_bf16(afr[m][0], bfr[n][0], acc[4 + m][n], 0, 0, 0);
        acc[4 + m][n] = __builtin_amdgcn_mfma_f32_16x16x32_bf16(afr[m][1], bfr[n][1], acc[4 + m][n], 0, 0, 0);
      }
    __builtin_amdgcn_s_setprio(0);
    asm volatile("s_waitcnt vmcnt(6)" ::: "memory");
    __builtin_amdgcn_s_barrier();
  }
#pragma unroll
  for (int M = 0; M < 8; ++M)
#pragma unroll
    for (int n = 0; n < 4; ++n)
#pragma unroll
      for (int r = 0; r < 4; ++r) {
        int row = m0 + wr * 128 + M * 16 + g * 4 + r;
        int col = n0 + wc * 64 + n * 16 + li;
        if constexpr (sizeof(CT) == 2)
          C[(size_t)row * ldc + col] = (CT)f2b(acc[M][n][r]);
        else
          C[(size_t)row * ldc + col] = acc[M][n][r];
      }
}

// ---------------- 256x192 4-phase bf16 GEMM: packs N=6144 into 512 blocks ----------------
__global__ __launch_bounds__(512, 2) void gemm192_kernel(const u16* __restrict__ A,
                                                         const u16* __restrict__ Bt,
                                                         u16* __restrict__ C,
                                                         int ldc, int K) {
  __shared__ u16 sh[57344]; // dbuf x [A 16384 | B 12288] u16 = 112 KiB
  const int tid = threadIdx.x;
  const int wave = tid >> 6, lane = tid & 63;
  const int g = lane >> 4, li = lane & 15;
  const int wr = wave >> 2, wc = wave & 3;
  const int m0 = blockIdx.y * 256, n0 = blockIdx.x * 192;
  const int r0 = tid >> 3;
  const int cs = ((tid & 7) ^ ((tid >> 3) & 7)) << 3;
  const u16* pA = A + (size_t)(m0 + r0) * K + cs;
  const u16* pB = Bt + (size_t)(n0 + r0) * K + cs;
  const int sl0 = (g ^ (li & 7)) << 3;
  const int sl1 = ((4 + g) ^ (li & 7)) << 3;
  const int nT = K >> 6;

  f32x4 acc[8][3];
  f32x4 zz = {0.f, 0.f, 0.f, 0.f};
#pragma unroll
  for (int M = 0; M < 8; ++M)
#pragma unroll
    for (int n = 0; n < 3; ++n) acc[M][n] = zz;

  auto stage64 = [&](const u16* src0, int ts, int dstU16) {
    __builtin_amdgcn_global_load_lds(
        (__attribute__((address_space(1))) void*)(src0 + (size_t)ts * 64),
        (__attribute__((address_space(3))) void*)(sh + dstU16 + wave * 512), 16, 0, 0);
  };

#pragma unroll
  for (int u = 0; u < 4; ++u) stage64(pA + (size_t)(u * 64) * K, 0, u * 4096);
#pragma unroll
  for (int u = 0; u < 3; ++u) stage64(pB + (size_t)(u * 64) * K, 0, 16384 + u * 4096);
#pragma unroll
  for (int u = 0; u < 4; ++u) stage64(pA + (size_t)(u * 64) * K, 1, 28672 + u * 4096);
#pragma unroll
  for (int u = 0; u < 3; ++u) stage64(pB + (size_t)(u * 64) * K, 1, 28672 + 16384 + u * 4096);
  asm volatile("s_waitcnt vmcnt(7)" ::: "memory");
  __builtin_amdgcn_s_barrier();

  bf16x8 afr[4][2], bfr[3][2];
  for (int t = 0; t < nT; ++t) {
    const int ab = (t & 1) * 28672, bb = ab + 16384;
    const int tn2 = (t + 2 < nT) ? t + 2 : nT - 1;
#pragma unroll
    for (int n = 0; n < 3; ++n) {
      int row = wc * 48 + n * 16 + li;
      bfr[n][0] = *(const bf16x8*)&sh[bb + row * 64 + sl0];
      bfr[n][1] = *(const bf16x8*)&sh[bb + row * 64 + sl1];
    }
#pragma unroll
    for (int m = 0; m < 4; ++m) {
      int row = wr * 128 + m * 16 + li;
      afr[m][0] = *(const bf16x8*)&sh[ab + row * 64 + sl0];
      afr[m][1] = *(const bf16x8*)&sh[ab + row * 64 + sl1];
    }
    __builtin_amdgcn_s_barrier();
    asm volatile("s_waitcnt lgkmcnt(0)" ::: "memory");
    __builtin_amdgcn_sched_barrier(0);
    __builtin_amdgcn_s_setprio(1);
#pragma unroll
    for (int m = 0; m < 4; ++m)
#pragma unroll
      for (int n = 0; n < 2; ++n) {
        acc[m][n] = __builtin_amdgcn_mfma_f32_16x16x32_bf16(afr[m][0], bfr[n][0], acc[m][n], 0, 0, 0);
        acc[m][n] = __builtin_amdgcn_mfma_f32_16x16x32_bf16(afr[m][1], bfr[n][1], acc[m][n], 0, 0, 0);
      }
    __builtin_amdgcn_s_setprio(0);
    __builtin_amdgcn_s_barrier();
    stage64(pB, tn2, bb);
    stage64(pB + (size_t)64 * K, tn2, bb + 4096);
    stage64(pA, tn2, ab);
    __builtin_amdgcn_s_barrier();
    __builtin_amdgcn_s_setprio(1);
#pragma unroll
    for (int m = 0; m < 4; ++m) {
      acc[m][2] = __builtin_amdgcn_mfma_f32_16x16x32_bf16(afr[m][0], bfr[2][0], acc[m][2], 0, 0, 0);
      acc[m][2] = __builtin_amdgcn_mfma_f32_16x16x32_bf16(afr[m][1], bfr[2][1], acc[m][2], 0, 0, 0);
    }
    __builtin_amdgcn_s_setprio(0);
    __builtin_amdgcn_s_barrier();
#pragma unroll
    for (int m = 0; m < 4; ++m) {
      int row = wr * 128 + 64 + m * 16 + li;
      afr[m][0] = *(const bf16x8*)&sh[ab + row * 64 + sl0];
      afr[m][1] = *(const bf16x8*)&sh[ab + row * 64 + sl1];
    }
    stage64(pB + (size_t)128 * K, tn2, bb + 8192);
    stage64(pA + (size_t)128 * K, tn2, ab + 8192);
    __builtin_amdgcn_s_barrier();
    asm volatile("s_waitcnt lgkmcnt(0)" ::: "memory");
    __builtin_amdgcn_sched_barrier(0);
    __builtin_amdgcn_s_setprio(1);
#pragma unroll
    for (int m = 0; m < 4; ++m)
#pragma unroll
      for (int n = 0; n < 2; ++n) {
        acc[4 + m][n] = __builtin_amdgcn_mfma_f32_16x16x32_bf16(afr[m][0], bfr[n][0], acc[4 + m][n], 0, 0, 0);
        acc[4 + m][n] = __builtin_amdgcn_mfma_f32_16x16x32_bf16(afr[m][1], bfr[n][1], acc[4 + m][n], 0, 0, 0);
      }
    __builtin_amdgcn_s_setprio(0);
    __builtin_amdgcn_s_barrier();
    stage64(pA + (size_t)64 * K, tn2, ab + 4096);
    stage64(pA + (size_t)192 * K, tn2, ab + 12288);
    __builtin_amdgcn_s_barrier();
    __builtin_amdgcn_s_setprio(1);
#pragma unroll
    for (int m = 0; m < 4; ++m) {
      acc[4 + m][2] = __builtin_amdgcn_mfma_f32_16x16x32_bf16(afr[m][0], bfr[2][0], acc[4 + m][2], 0, 0, 0);
      acc[4 + m][2] = __builtin_amdgcn_mfma_f32_16x16x32_bf16(afr[m][1], bfr[2][1], acc[4 + m][2], 0, 0, 0);
    }
    __builtin_amdgcn_s_setprio(0);
    asm volatile("s_waitcnt vmcnt(7)" ::: "memory");
    __builtin_amdgcn_s_barrier();
  }
#pragma unroll
  for (int M = 0; M < 8; ++M)
#pragma unroll
    for (int n = 0; n < 3; ++n)
#pragma unroll
      for (int r = 0; r < 4; ++r) {
        int row = m0 + wr * 128 + M * 16 + g * 4 + r;
        int col = n0 + wc * 48 + n * 16 + li;
        C[(size_t)row * ldc + col] = f2b(acc[M][n][r]);
      }
}

// ---------------- RoPE in place on fused qkv, bf16x8-vectorized ----------------
// Folds the attention scale 1/sqrt(HD) into the q heads (f32, single rounding).
__global__ __launch_bounds__(256) void rope_kernel(u16* __restrict__ qkv,
                                                   const float* __restrict__ cosp,
                                                   const float* __restrict__ sinp) {
  int idx = blockIdx.x * 256 + threadIdx.x; // B*T*(NH+NKV)*8
  int d8 = idx & 7;
  int rest = idx >> 3;
  int hh = rest % (NH + NKV);
  int bt = rest / (NH + NKV);
  if (bt >= B_SZ * T_SEQ) return;
  int tok = bt & (T_SEQ - 1);
  int d0 = d8 * 8;
  const float4* cp = (const float4*)(cosp + (size_t)tok * HDIM + d0);
  const float4* sp = (const float4*)(sinp + (size_t)tok * HDIM + d0);
  float4 cA = cp[0], cB = cp[1];
  float4 sA = sp[0], sB = sp[1];
  float cc[8] = {cA.x, cA.y, cA.z, cA.w, cB.x, cB.y, cB.z, cB.w};
  float ss[8] = {sA.x, sA.y, sA.z, sA.w, sB.x, sB.y, sB.z, sB.w};
  float scl = (hh < NH) ? SCALE : 1.0f;
  u16* base = qkv + (size_t)bt * QSTR + hh * HDIM;
  bf16x8 v1 = *(const bf16x8*)(base + d0);
  bf16x8 v2 = *(const bf16x8*)(base + d0 + 64);
  bf16x8 o1, o2;
#pragma unroll
  for (int j = 0; j < 8; ++j) {
    float xa = (float)v1[j], xb = (float)v2[j];
    o1[j] = (__bf16)((xa * cc[j] - xb * ss[j]) * scl);
    o2[j] = (__bf16)((xb * cc[j] + xa * ss[j]) * scl);
  }
  *(bf16x8*)(base + d0) = o1;
  *(bf16x8*)(base + d0 + 64) = o2;
}

// ---------------- flash attention, QB=128 (8 waves x 16 rows), KVB=64 ----------------
// Swapped QK^T (mfma(K,Q) -> S^T), lane-local softmax. NEW (R7): uniform tile list
// + double-buffered K/V with async global_load_lds staging overlapped under compute
// (T14); one s_barrier + vmcnt(0) per tile instead of two __syncthreads.
__global__ __launch_bounds__(512) void attn_kernel(const u16* __restrict__ qp,
                                                   const u16* __restrict__ kp,
                                                   const u16* __restrict__ vtp,
                                                   u16* __restrict__ ctx) {
  __shared__ u16 Kt[2][64 * 128];   // row-major, XOR-swizzled (via source)
  __shared__ u16 Vt[2][128 * 64];   // hd-major, XOR-swizzled
  __shared__ u16 Pl[8][16 * 64];    // per-wave P bounce, swizzled
  int tid = threadIdx.x;
  int w = tid >> 6, lane = tid & 63;
  int g = lane >> 4, li = lane & 15;
  int i0 = blockIdx.x * 128;
  int h = blockIdx.y, b = blockIdx.z;
  int kh = h >> 2; // repeat_interleave: q-head h -> kv-head h/4
  f32x4 zz = {0.f, 0.f, 0.f, 0.f};

  // Q fragments (B-operand; col=li=q, k=c*32+g*8+e); q pre-scaled by 1/sqrt(HD)
  bf16x8 qf[4];
  size_t qrow = (size_t)(b * T_SEQ + i0 + w * 16 + li) * QSTR + h * HDIM;
#pragma unroll
  for (int c = 0; c < 4; ++c) qf[c] = *(const bf16x8*)(qp + qrow + c * 32 + g * 8);

  f32x4 o[8];
#pragma unroll
  for (int f = 0; f < 8; ++f) o[f] = zz;
  float m_s = -1e30f, l_s = 0.f; // per-lane stats for q = i0 + w*16 + li
  const int irow = i0 + w * 16 + li;

  // Tile list: {0 (global sink)} ∪ {jlo .. i0+64 step 64}, jlo = max(0, i0-WINDOW).
  // Exactly reproduces the R6 keep-set: j0==0 always kept (NGLOB<64);
  // window tiles kept iff j0+63 > i0-WINDOW  <=>  j0 >= i0-WINDOW (multiples of 64).
  const int jlo = (i0 > WINDOW) ? (i0 - WINDOW) : 0;
  const int nglob = (jlo > 0) ? 1 : 0;
  const int ntiles = nglob + (i0 + 64 - jlo) / 64 + 1;

  auto j_of = [&](int t) { return (nglob && t == 0) ? 0 : jlo + (t - nglob) * 64; };

  auto stage = [&](int t, int buf) {
    int j0 = j_of(t);
#pragma unroll
    for (int i = 0; i < 2; ++i) {
      int o8 = tid + 512 * i;
      int krow = o8 >> 4, kch = o8 & 15;
      size_t gk = (size_t)(b * T_SEQ + j0 + krow) * QSTR + kh * HDIM + (kch ^ (krow & 7)) * 8;
      __builtin_amdgcn_global_load_lds((__attribute__((address_space(1))) void*)(kp + gk),
                                       (__attribute__((address_space(3))) void*)(Kt[buf] + o8 * 8),
                                       16, 0, 0);
      int vrow = o8 >> 3, vch = o8 & 7;
      size_t gv = ((size_t)(b * NKV + kh) * HDIM + vrow) * T_SEQ + j0 + (vch ^ (vrow & 7)) * 8;
      __builtin_amdgcn_global_load_lds((__attribute__((address_space(1))) void*)(vtp + gv),
                                       (__attribute__((address_space(3))) void*)(Vt[buf] + o8 * 8),
                                       16, 0, 0);
    }
  };

  // prologue: tile 0 resident in buf 0
  stage(0, 0);
  asm volatile("s_waitcnt vmcnt(0)" ::: "memory");
  __builtin_amdgcn_s_barrier();

  for (int t = 0; t < ntiles; ++t) {
    const int buf = t & 1;
    const int j0 = j_of(t);
    // issue next tile's staging into the other buffer (last read in iter t-1,
    // protected by that iteration's end barrier); lands under this tile's compute
    if (t + 1 < ntiles) stage(t + 1, buf ^ 1);

    // S^T = K @ Q^T : rows=keys (kb*16+g*4+r), cols=q (li)
    f32x4 s[4];
#pragma unroll
    for (int kb = 0; kb < 4; ++kb) s[kb] = zz;
#pragma unroll
    for (int c = 0; c < 4; ++c) {
      int hd0 = c * 32 + g * 8;
#pragma unroll
      for (int kb = 0; kb < 4; ++kb) {
        int key = kb * 16 + li;
        bf16x8 kf = *(const bf16x8*)&Kt[buf][(key * 128 + hd0) ^ ((key & 7) << 3)];
        s[kb] = __builtin_amdgcn_mfma_f32_16x16x32_bf16(kf, qf[c], s[kb], 0, 0, 0);
      }
    }

    // mask + online softmax: lane-local (q=li), all 16 rows in parallel
    float x[4][4];
    float mt = -1e30f;
#pragma unroll
    for (int kb = 0; kb < 4; ++kb)
#pragma unroll
      for (int r = 0; r < 4; ++r) {
        int j = j0 + kb * 16 + g * 4 + r;
        bool vm = (j <= irow) && ((j > irow - WINDOW) || (j < NGLOB));
        float xx = vm ? s[kb][r] : -1e30f;
        x[kb][r] = xx;
        mt = fmaxf(mt, xx);
      }
    mt = fmaxf(mt, __shfl_xor(mt, 16, 64));
    mt = fmaxf(mt, __shfl_xor(mt, 32, 64));
    float mn = fmaxf(m_s, mt);
    float corr = __expf(m_s - mn);
    m_s = mn;
    float rs = 0.f;
#pragma unroll
    for (int kb = 0; kb < 4; ++kb) {
      ushort4 pk;
#pragma unroll
      for (int r = 0; r < 4; ++r) {
        float p = __expf(x[kb][r] - mn);
        rs += p;
        ((u16*)&pk)[r] = f2b(p);
      }
      *(ushort4*)&Pl[w][(li * 64 + kb * 16 + g * 4) ^ ((li & 7) << 3)] = pk;
    }
    rs += __shfl_xor(rs, 16, 64);
    rs += __shfl_xor(rs, 32, 64);
    l_s = l_s * corr + rs;

    // redistribute corr to O-row owners (O row q = g*4+r, stats at lane li'=g*4+r)
    float c4[4];
#pragma unroll
    for (int r = 0; r < 4; ++r) c4[r] = __shfl(corr, g * 4 + r, 16);
#pragma unroll
    for (int f = 0; f < 8; ++f) {
      o[f][0] *= c4[0]; o[f][1] *= c4[1];
      o[f][2] *= c4[2]; o[f][3] *= c4[3];
    }

    // P A-frags (row=li=q): two k-chunks of 32
    bf16x8 pa0 = *(const bf16x8*)&Pl[w][(li * 64 + 0 + g * 8) ^ ((li & 7) << 3)];
    bf16x8 pa1 = *(const bf16x8*)&Pl[w][(li * 64 + 32 + g * 8) ^ ((li & 7) << 3)];

    // O += P @ V : B-frags are vector reads from hd-major Vt
#pragma unroll
    for (int f = 0; f < 8; ++f) {
      int hd = f * 16 + li;
      bf16x8 v0 = *(const bf16x8*)&Vt[buf][(hd * 64 + 0 + g * 8) ^ ((li & 7) << 3)];
      bf16x8 v1 = *(const bf16x8*)&Vt[buf][(hd * 64 + 32 + g * 8) ^ ((li & 7) << 3)];
      o[f] = __builtin_amdgcn_mfma_f32_16x16x32_bf16(pa0, v0, o[f], 0, 0, 0);
      o[f] = __builtin_amdgcn_mfma_f32_16x16x32_bf16(pa1, v1, o[f], 0, 0, 0);
    }

    // next tile staged (own loads drained) + everyone done reading buf
    asm volatile("s_waitcnt vmcnt(0)" ::: "memory");
    __builtin_amdgcn_s_barrier();
  }

  // epilogue: O rows q=g*4+r need l from lane li'=g*4+r
  float l4[4];
#pragma unroll
  for (int r = 0; r < 4; ++r) l4[r] = __shfl(l_s, g * 4 + r, 16);
#pragma unroll
  for (int f = 0; f < 8; ++f)
#pragma unroll
    for (int r = 0; r < 4; ++r) {
      size_t orow = (size_t)(b * T_SEQ + i0 + w * 16 + g * 4 + r) * (NH * HDIM) + h * HDIM + f * 16 + li;
      ctx[orow] = f2b(o[f][r] / l4[r]);
    }
}

extern "C" void kernel_launch(void* const* d_in, const int* in_sizes, int n_in,
                              void* d_out, int out_size, void* d_ws, size_t ws_size,
                              hipStream_t stream) {
  const float* x    = (const float*)d_in[0];
  const float* Wq   = (const float*)d_in[1];
  const float* Wk   = (const float*)d_in[2];
  const float* Wv   = (const float*)d_in[3];
  const float* Wo   = (const float*)d_in[4];
  const float* cosp = (const float*)d_in[5];
  const float* sinp = (const float*)d_in[6];
  // d_in[7] = mask: recomputed analytically in-kernel.

  char* ws = (char*)d_ws;
  u16* xb     = (u16*)(ws + 0ull);           // 32 MiB [4096,4096]
  u16* Wqkvt  = (u16*)(ws + 33554432ull);    // 48 MiB [6144,4096]
  u16* Wot    = (u16*)(ws + 83886080ull);    // 32 MiB [4096,4096]
  u16* qkv    = (u16*)(ws + 117440512ull);   // 48 MiB [4096,6144]
  u16* ctx    = xb;
  u16* vT     = Wqkvt;                        // 8 MiB [B][KH*HD][T]

  convert_bf16_kernel<<<16384, 256, 0, stream>>>(x, xb, 4194304);
  transpose_w_kernel<<<dim3(128, 128), 256, 0, stream>>>(Wq, Wqkvt, 4096, 4096);
  transpose_w_kernel<<<dim3(32, 128), 256, 0, stream>>>(Wk, Wqkvt + (size_t)4096 * 4096, 4096, 1024);
  transpose_w_kernel<<<dim3(32, 128), 256, 0, stream>>>(Wv, Wqkvt + (size_t)5120 * 4096, 4096, 1024);
  transpose_w_kernel<<<dim3(128, 128), 256, 0, stream>>>(Wo, Wot, 4096, 4096);

  gemm192_kernel<<<dim3(32, 16), 512, 0, stream>>>(xb, Wqkvt, qkv, QSTR, 4096);

  transpose_v_kernel<<<dim3(32, 64, 2), 256, 0, stream>>>(qkv + 5120, vT);

  rope_kernel<<<5120, 256, 0, stream>>>(qkv, cosp, sinp);

  attn_kernel<<<dim3(16, 32, 2), 512, 0, stream>>>(qkv, qkv + 4096, vT, ctx);

  gemm256_kernel<float><<<dim3(16, 16), 512, 0, stream>>>(ctx, Wot, (float*)d_out, 4096, 4096);
}

// Round 8
// 527.750 us; speedup vs baseline: 1.0575x; 1.0575x over previous
//
#include <hip/hip_runtime.h>
#include <stdint.h>

typedef unsigned short u16;
typedef __bf16 bf16x8 __attribute__((ext_vector_type(8)));
typedef float f32x4 __attribute__((ext_vector_type(4)));

#define D_MODEL 4096
#define T_SEQ   2048
#define B_SZ    2
#define NH      32
#define NKV     8
#define HDIM    128
#define WINDOW  1024
#define NGLOB   32
#define QSTR    6144   // fused qkv row stride: [q 4096 | k 1024 | v 1024]

static constexpr float SCALE = 0.08838834764831845f; // 1/sqrt(128)

__device__ __forceinline__ u16 f2b(float f) {
  __bf16 h = (__bf16)f;
  return __builtin_bit_cast(u16, h);
}

// ---------------- x f32 -> bf16 (vectorized) ----------------
__global__ __launch_bounds__(256) void convert_bf16_kernel(const float* __restrict__ in,
                                                           u16* __restrict__ outp, int n4) {
  int i = blockIdx.x * 256 + threadIdx.x;
  if (i >= n4) return;
  float4 v = ((const float4*)in)[i];
  ushort4 o;
  o.x = f2b(v.x); o.y = f2b(v.y); o.z = f2b(v.z); o.w = f2b(v.w);
  ((ushort4*)outp)[i] = o;
}

// ---------------- W [K,N] f32 -> Wt [N,K] bf16 ----------------
__global__ __launch_bounds__(256) void transpose_w_kernel(const float* __restrict__ W,
                                                          u16* __restrict__ Wt, int Kd, int Nd) {
  __shared__ float tile[32][33];
  int tx = threadIdx.x & 31, ty = threadIdx.x >> 5;
  int bx = blockIdx.x * 32; // N
  int by = blockIdx.y * 32; // K
#pragma unroll
  for (int i = 0; i < 4; ++i)
    tile[ty + i * 8][tx] = W[(size_t)(by + ty + i * 8) * Nd + bx + tx];
  __syncthreads();
#pragma unroll
  for (int i = 0; i < 4; ++i)
    Wt[(size_t)(bx + ty + i * 8) * Kd + by + tx] = f2b(tile[tx][ty + i * 8]);
}

// ---------------- v slice of qkv -> vT [B][KH*HD][T] bf16 ----------------
__global__ __launch_bounds__(256) void transpose_v_kernel(const u16* __restrict__ in,
                                                          u16* __restrict__ outp) {
  __shared__ u16 tile[32][33];
  int tx = threadIdx.x & 31, ty = threadIdx.x >> 5;
  int x0 = blockIdx.x * 32; // hd' = kh*128+hd (0..1023)
  int t0 = blockIdx.y * 32; // t
  int b = blockIdx.z;
  const u16* src = in + (size_t)b * T_SEQ * QSTR;
  u16* dst = outp + (size_t)b * (NKV * HDIM) * T_SEQ;
#pragma unroll
  for (int i = 0; i < 4; ++i)
    tile[ty + i * 8][tx] = src[(size_t)(t0 + ty + i * 8) * QSTR + x0 + tx];
  __syncthreads();
#pragma unroll
  for (int i = 0; i < 4; ++i)
    dst[(size_t)(x0 + ty + i * 8) * T_SEQ + t0 + tx] = tile[tx][ty + i * 8];
}

// ---------------- 256x256 8-phase bf16 GEMM (proven): C = A @ Bt^T ----------------
template <typename CT>
__global__ __launch_bounds__(512, 2) void gemm256_kernel(const u16* __restrict__ A,
                                                         const u16* __restrict__ Bt,
                                                         CT* __restrict__ C,
                                                         int ldc, int K) {
  __shared__ u16 sh[65536]; // [buf:2][A 16384 | B 16384] u16 = 128 KiB
  const int tid = threadIdx.x;
  const int wave = tid >> 6, lane = tid & 63;
  const int g = lane >> 4, li = lane & 15;
  const int wr = wave >> 2, wc = wave & 3;
  const int m0 = blockIdx.y * 256, n0 = blockIdx.x * 256;
  const int r0 = tid >> 3;
  const int cs = ((tid & 7) ^ ((tid >> 3) & 7)) << 3;
  const u16* pA = A + (size_t)(m0 + r0) * K + cs;
  const u16* pB = Bt + (size_t)(n0 + r0) * K + cs;
  const int sl0 = (g ^ (li & 7)) << 3;
  const int sl1 = ((4 + g) ^ (li & 7)) << 3;
  const int nT = K >> 6;

  f32x4 acc[8][4];
  f32x4 zz = {0.f, 0.f, 0.f, 0.f};
#pragma unroll
  for (int M = 0; M < 8; ++M)
#pragma unroll
    for (int n = 0; n < 4; ++n) acc[M][n] = zz;

  auto stage = [&](const u16* src0, int ts, int dstBase) {
#pragma unroll
    for (int i = 0; i < 2; ++i) {
      const u16* s = src0 + (size_t)(i * 64) * K + ts * 64;
      __builtin_amdgcn_global_load_lds((__attribute__((address_space(1))) void*)s,
                                       (__attribute__((address_space(3))) void*)(sh + dstBase + i * 4096 + wave * 512),
                                       16, 0, 0);
    }
  };

  stage(pA, 0, 0);
  stage(pA + (size_t)128 * K, 0, 8192);
  stage(pB, 0, 16384);
  stage(pB + (size_t)128 * K, 0, 24576);
  stage(pB, 1, 32768 + 16384);
  stage(pB + (size_t)128 * K, 1, 32768 + 24576);
  stage(pA, 1, 32768);
  asm volatile("s_waitcnt vmcnt(6)" ::: "memory");
  __builtin_amdgcn_s_barrier();

  bf16x8 afr[4][2], bfr[4][2];
  for (int t = 0; t < nT; ++t) {
    const int cur = t & 1;
    const int ab = cur * 32768, bb = ab + 16384;
    const int nb = (cur ^ 1) * 32768;
    const int tn1 = (t + 1 < nT) ? t + 1 : nT - 1;
    const int tn2 = (t + 2 < nT) ? t + 2 : nT - 1;
#pragma unroll
    for (int n = 0; n < 4; ++n) {
      int row = wc * 64 + n * 16 + li;
      bfr[n][0] = *(const bf16x8*)&sh[bb + row * 64 + sl0];
      bfr[n][1] = *(const bf16x8*)&sh[bb + row * 64 + sl1];
    }
#pragma unroll
    for (int m = 0; m < 4; ++m) {
      int row = wr * 128 + m * 16 + li;
      afr[m][0] = *(const bf16x8*)&sh[ab + row * 64 + sl0];
      afr[m][1] = *(const bf16x8*)&sh[ab + row * 64 + sl1];
    }
    stage(pA + (size_t)128 * K, tn1, nb + 8192);
    __builtin_amdgcn_s_barrier();
    asm volatile("s_waitcnt lgkmcnt(0)" ::: "memory");
    __builtin_amdgcn_sched_barrier(0);
    __builtin_amdgcn_s_setprio(1);
#pragma unroll
    for (int m = 0; m < 4; ++m)
#pragma unroll
      for (int n = 0; n < 2; ++n) {
        acc[m][n] = __builtin_amdgcn_mfma_f32_16x16x32_bf16(afr[m][0], bfr[n][0], acc[m][n], 0, 0, 0);
        acc[m][n] = __builtin_amdgcn_mfma_f32_16x16x32_bf16(afr[m][1], bfr[n][1], acc[m][n], 0, 0, 0);
      }
    __builtin_amdgcn_s_setprio(0);
    __builtin_amdgcn_s_barrier();
    stage(pB, tn2, bb);
    __builtin_amdgcn_s_barrier();
    __builtin_amdgcn_s_setprio(1);
#pragma unroll
    for (int m = 0; m < 4; ++m)
#pragma unroll
      for (int n = 2; n < 4; ++n) {
        acc[m][n] = __builtin_amdgcn_mfma_f32_16x16x32_bf16(afr[m][0], bfr[n][0], acc[m][n], 0, 0, 0);
        acc[m][n] = __builtin_amdgcn_mfma_f32_16x16x32_bf16(afr[m][1], bfr[n][1], acc[m][n], 0, 0, 0);
      }
    __builtin_amdgcn_s_setprio(0);
    __builtin_amdgcn_s_barrier();
#pragma unroll
    for (int m = 0; m < 4; ++m) {
      int row = wr * 128 + 64 + m * 16 + li;
      afr[m][0] = *(const bf16x8*)&sh[ab + row * 64 + sl0];
      afr[m][1] = *(const bf16x8*)&sh[ab + row * 64 + sl1];
    }
    stage(pB + (size_t)128 * K, tn2, bb + 8192);
    __builtin_amdgcn_s_barrier();
    asm volatile("s_waitcnt lgkmcnt(0)" ::: "memory");
    __builtin_amdgcn_sched_barrier(0);
    __builtin_amdgcn_s_setprio(1);
#pragma unroll
    for (int m = 0; m < 4; ++m)
#pragma unroll
      for (int n = 0; n < 2; ++n) {
        acc[4 + m][n] = __builtin_amdgcn_mfma_f32_16x16x32_bf16(afr[m][0], bfr[n][0], acc[4 + m][n], 0, 0, 0);
        acc[4 + m][n] = __builtin_amdgcn_mfma_f32_16x16x32_bf16(afr[m][1], bfr[n][1], acc[4 + m][n], 0, 0, 0);
      }
    __builtin_amdgcn_s_setprio(0);
    __builtin_amdgcn_s_barrier();
    stage(pA, tn2, ab);
    __builtin_amdgcn_s_barrier();
    __builtin_amdgcn_s_setprio(1);
#pragma unroll
    for (int m = 0; m < 4; ++m)
#pragma unroll
      for (int n = 2; n < 4; ++n) {
        acc[4 + m][n] = __builtin_amdgcn_mfma_f32_16x16x32_bf16(afr[m][0], bfr[n][0], acc[4 + m][n], 0, 0, 0);
        acc[4 + m][n] = __builtin_amdgcn_mfma_f32_16x16x32_bf16(afr[m][1], bfr[n][1], acc[4 + m][n], 0, 0, 0);
      }
    __builtin_amdgcn_s_setprio(0);
    asm volatile("s_waitcnt vmcnt(6)" ::: "memory");
    __builtin_amdgcn_s_barrier();
  }
#pragma unroll
  for (int M = 0; M < 8; ++M)
#pragma unroll
    for (int n = 0; n < 4; ++n)
#pragma unroll
      for (int r = 0; r < 4; ++r) {
        int row = m0 + wr * 128 + M * 16 + g * 4 + r;
        int col = n0 + wc * 64 + n * 16 + li;
        if constexpr (sizeof(CT) == 2)
          C[(size_t)row * ldc + col] = (CT)f2b(acc[M][n][r]);
        else
          C[(size_t)row * ldc + col] = acc[M][n][r];
      }
}

// ---------------- 256x192 4-phase bf16 GEMM: packs N=6144 into 512 blocks ----------------
__global__ __launch_bounds__(512, 2) void gemm192_kernel(const u16* __restrict__ A,
                                                         const u16* __restrict__ Bt,
                                                         u16* __restrict__ C,
                                                         int ldc, int K) {
  __shared__ u16 sh[57344]; // dbuf x [A 16384 | B 12288] u16 = 112 KiB
  const int tid = threadIdx.x;
  const int wave = tid >> 6, lane = tid & 63;
  const int g = lane >> 4, li = lane & 15;
  const int wr = wave >> 2, wc = wave & 3;
  const int m0 = blockIdx.y * 256, n0 = blockIdx.x * 192;
  const int r0 = tid >> 3;
  const int cs = ((tid & 7) ^ ((tid >> 3) & 7)) << 3;
  const u16* pA = A + (size_t)(m0 + r0) * K + cs;
  const u16* pB = Bt + (size_t)(n0 + r0) * K + cs;
  const int sl0 = (g ^ (li & 7)) << 3;
  const int sl1 = ((4 + g) ^ (li & 7)) << 3;
  const int nT = K >> 6;

  f32x4 acc[8][3];
  f32x4 zz = {0.f, 0.f, 0.f, 0.f};
#pragma unroll
  for (int M = 0; M < 8; ++M)
#pragma unroll
    for (int n = 0; n < 3; ++n) acc[M][n] = zz;

  auto stage64 = [&](const u16* src0, int ts, int dstU16) {
    __builtin_amdgcn_global_load_lds(
        (__attribute__((address_space(1))) void*)(src0 + (size_t)ts * 64),
        (__attribute__((address_space(3))) void*)(sh + dstU16 + wave * 512), 16, 0, 0);
  };

#pragma unroll
  for (int u = 0; u < 4; ++u) stage64(pA + (size_t)(u * 64) * K, 0, u * 4096);
#pragma unroll
  for (int u = 0; u < 3; ++u) stage64(pB + (size_t)(u * 64) * K, 0, 16384 + u * 4096);
#pragma unroll
  for (int u = 0; u < 4; ++u) stage64(pA + (size_t)(u * 64) * K, 1, 28672 + u * 4096);
#pragma unroll
  for (int u = 0; u < 3; ++u) stage64(pB + (size_t)(u * 64) * K, 1, 28672 + 16384 + u * 4096);
  asm volatile("s_waitcnt vmcnt(7)" ::: "memory");
  __builtin_amdgcn_s_barrier();

  bf16x8 afr[4][2], bfr[3][2];
  for (int t = 0; t < nT; ++t) {
    const int ab = (t & 1) * 28672, bb = ab + 16384;
    const int tn2 = (t + 2 < nT) ? t + 2 : nT - 1;
#pragma unroll
    for (int n = 0; n < 3; ++n) {
      int row = wc * 48 + n * 16 + li;
      bfr[n][0] = *(const bf16x8*)&sh[bb + row * 64 + sl0];
      bfr[n][1] = *(const bf16x8*)&sh[bb + row * 64 + sl1];
    }
#pragma unroll
    for (int m = 0; m < 4; ++m) {
      int row = wr * 128 + m * 16 + li;
      afr[m][0] = *(const bf16x8*)&sh[ab + row * 64 + sl0];
      afr[m][1] = *(const bf16x8*)&sh[ab + row * 64 + sl1];
    }
    __builtin_amdgcn_s_barrier();
    asm volatile("s_waitcnt lgkmcnt(0)" ::: "memory");
    __builtin_amdgcn_sched_barrier(0);
    __builtin_amdgcn_s_setprio(1);
#pragma unroll
    for (int m = 0; m < 4; ++m)
#pragma unroll
      for (int n = 0; n < 2; ++n) {
        acc[m][n] = __builtin_amdgcn_mfma_f32_16x16x32_bf16(afr[m][0], bfr[n][0], acc[m][n], 0, 0, 0);
        acc[m][n] = __builtin_amdgcn_mfma_f32_16x16x32_bf16(afr[m][1], bfr[n][1], acc[m][n], 0, 0, 0);
      }
    __builtin_amdgcn_s_setprio(0);
    __builtin_amdgcn_s_barrier();
    stage64(pB, tn2, bb);
    stage64(pB + (size_t)64 * K, tn2, bb + 4096);
    stage64(pA, tn2, ab);
    __builtin_amdgcn_s_barrier();
    __builtin_amdgcn_s_setprio(1);
#pragma unroll
    for (int m = 0; m < 4; ++m) {
      acc[m][2] = __builtin_amdgcn_mfma_f32_16x16x32_bf16(afr[m][0], bfr[2][0], acc[m][2], 0, 0, 0);
      acc[m][2] = __builtin_amdgcn_mfma_f32_16x16x32_bf16(afr[m][1], bfr[2][1], acc[m][2], 0, 0, 0);
    }
    __builtin_amdgcn_s_setprio(0);
    __builtin_amdgcn_s_barrier();
#pragma unroll
    for (int m = 0; m < 4; ++m) {
      int row = wr * 128 + 64 + m * 16 + li;
      afr[m][0] = *(const bf16x8*)&sh[ab + row * 64 + sl0];
      afr[m][1] = *(const bf16x8*)&sh[ab + row * 64 + sl1];
    }
    stage64(pB + (size_t)128 * K, tn2, bb + 8192);
    stage64(pA + (size_t)128 * K, tn2, ab + 8192);
    __builtin_amdgcn_s_barrier();
    asm volatile("s_waitcnt lgkmcnt(0)" ::: "memory");
    __builtin_amdgcn_sched_barrier(0);
    __builtin_amdgcn_s_setprio(1);
#pragma unroll
    for (int m = 0; m < 4; ++m)
#pragma unroll
      for (int n = 0; n < 2; ++n) {
        acc[4 + m][n] = __builtin_amdgcn_mfma_f32_16x16x32_bf16(afr[m][0], bfr[n][0], acc[4 + m][n], 0, 0, 0);
        acc[4 + m][n] = __builtin_amdgcn_mfma_f32_16x16x32_bf16(afr[m][1], bfr[n][1], acc[4 + m][n], 0, 0, 0);
      }
    __builtin_amdgcn_s_setprio(0);
    __builtin_amdgcn_s_barrier();
    stage64(pA + (size_t)64 * K, tn2, ab + 4096);
    stage64(pA + (size_t)192 * K, tn2, ab + 12288);
    __builtin_amdgcn_s_barrier();
    __builtin_amdgcn_s_setprio(1);
#pragma unroll
    for (int m = 0; m < 4; ++m) {
      acc[4 + m][2] = __builtin_amdgcn_mfma_f32_16x16x32_bf16(afr[m][0], bfr[2][0], acc[4 + m][2], 0, 0, 0);
      acc[4 + m][2] = __builtin_amdgcn_mfma_f32_16x16x32_bf16(afr[m][1], bfr[2][1], acc[4 + m][2], 0, 0, 0);
    }
    __builtin_amdgcn_s_setprio(0);
    asm volatile("s_waitcnt vmcnt(7)" ::: "memory");
    __builtin_amdgcn_s_barrier();
  }
#pragma unroll
  for (int M = 0; M < 8; ++M)
#pragma unroll
    for (int n = 0; n < 3; ++n)
#pragma unroll
      for (int r = 0; r < 4; ++r) {
        int row = m0 + wr * 128 + M * 16 + g * 4 + r;
        int col = n0 + wc * 48 + n * 16 + li;
        C[(size_t)row * ldc + col] = f2b(acc[M][n][r]);
      }
}

// ---------------- RoPE in place on fused qkv, bf16x8-vectorized ----------------
// Folds the attention scale 1/sqrt(HD) into the q heads (f32, single rounding).
__global__ __launch_bounds__(256) void rope_kernel(u16* __restrict__ qkv,
                                                   const float* __restrict__ cosp,
                                                   const float* __restrict__ sinp) {
  int idx = blockIdx.x * 256 + threadIdx.x; // B*T*(NH+NKV)*8
  int d8 = idx & 7;
  int rest = idx >> 3;
  int hh = rest % (NH + NKV);
  int bt = rest / (NH + NKV);
  if (bt >= B_SZ * T_SEQ) return;
  int tok = bt & (T_SEQ - 1);
  int d0 = d8 * 8;
  const float4* cp = (const float4*)(cosp + (size_t)tok * HDIM + d0);
  const float4* sp = (const float4*)(sinp + (size_t)tok * HDIM + d0);
  float4 cA = cp[0], cB = cp[1];
  float4 sA = sp[0], sB = sp[1];
  float cc[8] = {cA.x, cA.y, cA.z, cA.w, cB.x, cB.y, cB.z, cB.w};
  float ss[8] = {sA.x, sA.y, sA.z, sA.w, sB.x, sB.y, sB.z, sB.w};
  float scl = (hh < NH) ? SCALE : 1.0f;
  u16* base = qkv + (size_t)bt * QSTR + hh * HDIM;
  bf16x8 v1 = *(const bf16x8*)(base + d0);
  bf16x8 v2 = *(const bf16x8*)(base + d0 + 64);
  bf16x8 o1, o2;
#pragma unroll
  for (int j = 0; j < 8; ++j) {
    float xa = (float)v1[j], xb = (float)v2[j];
    o1[j] = (__bf16)((xa * cc[j] - xb * ss[j]) * scl);
    o2[j] = (__bf16)((xb * cc[j] + xa * ss[j]) * scl);
  }
  *(bf16x8*)(base + d0) = o1;
  *(bf16x8*)(base + d0 + 64) = o2;
}

// ---------------- flash attention, QB=256 (8 waves x 32 q-rows), KVB=64 ----------------
// R8: 32 q-rows/wave (2 x 16-row subblocks) -> every K/V LDS read feeds 2 MFMAs,
// halving per-q LDS traffic (the R7 bottleneck: 8 waves re-reading identical tiles).
// Swapped QK^T, lane-local softmax per subblock; K/V double-buffered async staging.
__global__ __launch_bounds__(512) void attn_kernel(const u16* __restrict__ qp,
                                                   const u16* __restrict__ kp,
                                                   const u16* __restrict__ vtp,
                                                   u16* __restrict__ ctx) {
  __shared__ u16 Kt[2][64 * 128];   // row-major, XOR-swizzled (via source)
  __shared__ u16 Vt[2][128 * 64];   // hd-major, XOR-swizzled
  __shared__ u16 Pl[8][16 * 64];    // per-wave P bounce, reused across subblocks
  int tid = threadIdx.x;
  int w = tid >> 6, lane = tid & 63;
  int g = lane >> 4, li = lane & 15;
  int i0 = blockIdx.x * 256;
  int h = blockIdx.y, b = blockIdx.z;
  int kh = h >> 2; // repeat_interleave: q-head h -> kv-head h/4
  f32x4 zz = {0.f, 0.f, 0.f, 0.f};

  // Q fragments for both 16-row subblocks (B-operand; col=li=q); q pre-scaled
  bf16x8 qf0[4], qf1[4];
  size_t qr0 = (size_t)(b * T_SEQ + i0 + w * 32 + li) * QSTR + h * HDIM;
  size_t qr1 = qr0 + (size_t)16 * QSTR;
#pragma unroll
  for (int c = 0; c < 4; ++c) {
    qf0[c] = *(const bf16x8*)(qp + qr0 + c * 32 + g * 8);
    qf1[c] = *(const bf16x8*)(qp + qr1 + c * 32 + g * 8);
  }

  f32x4 o0[8], o1[8];
#pragma unroll
  for (int f = 0; f < 8; ++f) { o0[f] = zz; o1[f] = zz; }
  float m_s0 = -1e30f, l_s0 = 0.f, m_s1 = -1e30f, l_s1 = 0.f;
  const int ir0 = i0 + w * 32 + li, ir1 = ir0 + 16;

  // Tile list: {0 (global sink)} ∪ {jlo .. i0+192 step 64}, jlo = max(0, i0-WINDOW).
  // Keep-set: j0 < NGLOB or j0+63 > i0-WINDOW (lower bound from LOWEST row i0).
  const int jlo = (i0 > WINDOW) ? (i0 - WINDOW) : 0;
  const int nglob = (jlo > 0) ? 1 : 0;
  const int ntiles = nglob + (i0 + 192 - jlo) / 64 + 1;

  auto j_of = [&](int t) { return (nglob && t == 0) ? 0 : jlo + (t - nglob) * 64; };

  auto stage = [&](int t, int buf) {
    int j0 = j_of(t);
#pragma unroll
    for (int i = 0; i < 2; ++i) {
      int o8 = tid + 512 * i;
      int krow = o8 >> 4, kch = o8 & 15;
      size_t gk = (size_t)(b * T_SEQ + j0 + krow) * QSTR + kh * HDIM + (kch ^ (krow & 7)) * 8;
      __builtin_amdgcn_global_load_lds((__attribute__((address_space(1))) void*)(kp + gk),
                                       (__attribute__((address_space(3))) void*)(Kt[buf] + o8 * 8),
                                       16, 0, 0);
      int vrow = o8 >> 3, vch = o8 & 7;
      size_t gv = ((size_t)(b * NKV + kh) * HDIM + vrow) * T_SEQ + j0 + (vch ^ (vrow & 7)) * 8;
      __builtin_amdgcn_global_load_lds((__attribute__((address_space(1))) void*)(vtp + gv),
                                       (__attribute__((address_space(3))) void*)(Vt[buf] + o8 * 8),
                                       16, 0, 0);
    }
  };

  stage(0, 0);
  asm volatile("s_waitcnt vmcnt(0)" ::: "memory");
  __builtin_amdgcn_s_barrier();

  for (int t = 0; t < ntiles; ++t) {
    const int buf = t & 1;
    const int j0 = j_of(t);
    if (t + 1 < ntiles) stage(t + 1, buf ^ 1);

    // S^T = K @ Q^T for both subblocks: each kf read feeds 2 MFMAs
    f32x4 s0[4], s1[4];
#pragma unroll
    for (int kb = 0; kb < 4; ++kb) { s0[kb] = zz; s1[kb] = zz; }
#pragma unroll
    for (int c = 0; c < 4; ++c) {
      int hd0 = c * 32 + g * 8;
#pragma unroll
      for (int kb = 0; kb < 4; ++kb) {
        int key = kb * 16 + li;
        bf16x8 kf = *(const bf16x8*)&Kt[buf][(key * 128 + hd0) ^ ((key & 7) << 3)];
        s0[kb] = __builtin_amdgcn_mfma_f32_16x16x32_bf16(kf, qf0[c], s0[kb], 0, 0, 0);
        s1[kb] = __builtin_amdgcn_mfma_f32_16x16x32_bf16(kf, qf1[c], s1[kb], 0, 0, 0);
      }
    }

    // mask + online softmax + P->LDS + A-frag read, per subblock (Pl reused;
    // compiler orders the WAR on Pl via lgkmcnt)
    bf16x8 pa00, pa01, pa10, pa11;
    auto softmax_p = [&](f32x4* s, int irow, float& m_s, float& l_s,
                         bf16x8& paA, bf16x8& paB, f32x4* o) {
      float x[4][4];
      float mt = -1e30f;
#pragma unroll
      for (int kb = 0; kb < 4; ++kb)
#pragma unroll
        for (int r = 0; r < 4; ++r) {
          int j = j0 + kb * 16 + g * 4 + r;
          bool vm = (j <= irow) && ((j > irow - WINDOW) || (j < NGLOB));
          float xx = vm ? s[kb][r] : -1e30f;
          x[kb][r] = xx;
          mt = fmaxf(mt, xx);
        }
      mt = fmaxf(mt, __shfl_xor(mt, 16, 64));
      mt = fmaxf(mt, __shfl_xor(mt, 32, 64));
      float mn = fmaxf(m_s, mt);
      float corr = __expf(m_s - mn);
      m_s = mn;
      float rs = 0.f;
#pragma unroll
      for (int kb = 0; kb < 4; ++kb) {
        ushort4 pk;
#pragma unroll
        for (int r = 0; r < 4; ++r) {
          float p = __expf(x[kb][r] - mn);
          rs += p;
          ((u16*)&pk)[r] = f2b(p);
        }
        *(ushort4*)&Pl[w][(li * 64 + kb * 16 + g * 4) ^ ((li & 7) << 3)] = pk;
      }
      rs += __shfl_xor(rs, 16, 64);
      rs += __shfl_xor(rs, 32, 64);
      l_s = l_s * corr + rs;
      float c4[4];
#pragma unroll
      for (int r = 0; r < 4; ++r) c4[r] = __shfl(corr, g * 4 + r, 16);
#pragma unroll
      for (int f = 0; f < 8; ++f) {
        o[f][0] *= c4[0]; o[f][1] *= c4[1];
        o[f][2] *= c4[2]; o[f][3] *= c4[3];
      }
      paA = *(const bf16x8*)&Pl[w][(li * 64 + 0 + g * 8) ^ ((li & 7) << 3)];
      paB = *(const bf16x8*)&Pl[w][(li * 64 + 32 + g * 8) ^ ((li & 7) << 3)];
    };
    softmax_p(s0, ir0, m_s0, l_s0, pa00, pa01, o0);
    softmax_p(s1, ir1, m_s1, l_s1, pa10, pa11, o1);

    // O += P @ V : each vf read feeds 2 MFMAs (both subblocks)
#pragma unroll
    for (int f = 0; f < 8; ++f) {
      int hd = f * 16 + li;
      bf16x8 v0 = *(const bf16x8*)&Vt[buf][(hd * 64 + 0 + g * 8) ^ ((li & 7) << 3)];
      bf16x8 v1 = *(const bf16x8*)&Vt[buf][(hd * 64 + 32 + g * 8) ^ ((li & 7) << 3)];
      o0[f] = __builtin_amdgcn_mfma_f32_16x16x32_bf16(pa00, v0, o0[f], 0, 0, 0);
      o0[f] = __builtin_amdgcn_mfma_f32_16x16x32_bf16(pa01, v1, o0[f], 0, 0, 0);
      o1[f] = __builtin_amdgcn_mfma_f32_16x16x32_bf16(pa10, v0, o1[f], 0, 0, 0);
      o1[f] = __builtin_amdgcn_mfma_f32_16x16x32_bf16(pa11, v1, o1[f], 0, 0, 0);
    }

    asm volatile("s_waitcnt vmcnt(0)" ::: "memory");
    __builtin_amdgcn_s_barrier();
  }

  // epilogue: O rows q=g*4+r need l from lane li'=g*4+r, per subblock
  float l40[4], l41[4];
#pragma unroll
  for (int r = 0; r < 4; ++r) {
    l40[r] = __shfl(l_s0, g * 4 + r, 16);
    l41[r] = __shfl(l_s1, g * 4 + r, 16);
  }
#pragma unroll
  for (int f = 0; f < 8; ++f)
#pragma unroll
    for (int r = 0; r < 4; ++r) {
      size_t row0 = (size_t)(b * T_SEQ + i0 + w * 32 + g * 4 + r) * (NH * HDIM) + h * HDIM + f * 16 + li;
      ctx[row0] = f2b(o0[f][r] / l40[r]);
      size_t row1 = row0 + (size_t)16 * (NH * HDIM);
      ctx[row1] = f2b(o1[f][r] / l41[r]);
    }
}

extern "C" void kernel_launch(void* const* d_in, const int* in_sizes, int n_in,
                              void* d_out, int out_size, void* d_ws, size_t ws_size,
                              hipStream_t stream) {
  const float* x    = (const float*)d_in[0];
  const float* Wq   = (const float*)d_in[1];
  const float* Wk   = (const float*)d_in[2];
  const float* Wv   = (const float*)d_in[3];
  const float* Wo   = (const float*)d_in[4];
  const float* cosp = (const float*)d_in[5];
  const float* sinp = (const float*)d_in[6];
  // d_in[7] = mask: recomputed analytically in-kernel.

  char* ws = (char*)d_ws;
  u16* xb     = (u16*)(ws + 0ull);           // 32 MiB [4096,4096]
  u16* Wqkvt  = (u16*)(ws + 33554432ull);    // 48 MiB [6144,4096]
  u16* Wot    = (u16*)(ws + 83886080ull);    // 32 MiB [4096,4096]
  u16* qkv    = (u16*)(ws + 117440512ull);   // 48 MiB [4096,6144]
  u16* ctx    = xb;
  u16* vT     = Wqkvt;                        // 8 MiB [B][KH*HD][T]

  convert_bf16_kernel<<<16384, 256, 0, stream>>>(x, xb, 4194304);
  transpose_w_kernel<<<dim3(128, 128), 256, 0, stream>>>(Wq, Wqkvt, 4096, 4096);
  transpose_w_kernel<<<dim3(32, 128), 256, 0, stream>>>(Wk, Wqkvt + (size_t)4096 * 4096, 4096, 1024);
  transpose_w_kernel<<<dim3(32, 128), 256, 0, stream>>>(Wv, Wqkvt + (size_t)5120 * 4096, 4096, 1024);
  transpose_w_kernel<<<dim3(128, 128), 256, 0, stream>>>(Wo, Wot, 4096, 4096);

  gemm192_kernel<<<dim3(32, 16), 512, 0, stream>>>(xb, Wqkvt, qkv, QSTR, 4096);

  transpose_v_kernel<<<dim3(32, 64, 2), 256, 0, stream>>>(qkv + 5120, vT);

  rope_kernel<<<5120, 256, 0, stream>>>(qkv, cosp, sinp);

  attn_kernel<<<dim3(8, 32, 2), 512, 0, stream>>>(qkv, qkv + 4096, vT, ctx);

  gemm256_kernel<float><<<dim3(16, 16), 512, 0, stream>>>(ctx, Wot, (float*)d_out, 4096, 4096);
}